// Round 11
// baseline (163.938 us; speedup 1.0000x reference)
//
#include <hip/hip_runtime.h>
#include <math.h>

#define DD 160
#define HH 160
#define WW 160
#define NB 2
#define NEL (NB*DD*HH*WW)   // 8,192,000 voxels

#define XT 32               // x outputs per block
#define YT 16               // y outputs per block (4 waves x 4-row strips)
#define ZC 16               // z outputs per block
#define NTHR 256
#define NZCH (DD/ZC)        // 10
#define GX (WW/XT)          // 5
#define GY (HH/YT)          // 10
#define NBLK (GX*GY*NB*NZCH)   // 1000 blocks x 4 waves
#define NPART (NBLK*4)         // per-WAVE partials (no cross-wave reduce)

#define SR 10               // staged halo rows per wave strip (4 + 6)
#define CP 35               // c4 physical pitch in float4 (32 + swizzle)

typedef float v2f __attribute__((ext_vector_type(2)));

struct G7 { float g[7]; };

// Fully fused separable 3D SSIM, v10 = BARRIER-FREE wave-private strips.
//  R8 post-mortem: VALU 29.5us + LDS 23us vs dur 59us -> ~50% stall, and
//  the stall is the per-slice __syncthreads convoy (4-wave rendezvous with
//  full vmcnt/lgkmcnt drain) + wave 3 idle during B (jobs < 256).
//  This version: each WAVE owns a 4-row y-strip with a private 10-row halo
//  and a private c4 LDS region. x-conv (80 jobs = 64 + 16) and y-conv both
//  happen within the wave; ds_write->ds_read ordering within one wave is
//  guaranteed by the in-order per-wave DS pipe (compiler lgkmcnt) -> ZERO
//  __syncthreads in the K-loop, single c4 buffer, waves fully self-paced.
//  Cost accepted: x-conv halo amortization 2.5x vs 1.375x (+~15% VALU),
//  LDS writes +21%. Frozen: XCD swizzle, v2f pk-fma, c4 column swizzle,
//  z register rings, in-register SSIM; per-wave partials (no final barrier).
__global__ __launch_bounds__(NTHR, 4) void ssim_fused(
        const float* __restrict__ p, const float* __restrict__ t,
        float* __restrict__ partial, G7 gw) {
    const int tid  = threadIdx.x;
    const int lane = tid & 63;
    const int wv   = tid >> 6;           // wave = strip

    // XCD-aware work remap (bijection on [0,NBLK))
    const int flat = blockIdx.x;
    const int w = (flat & 7) * (NBLK / 8) + (flat >> 3);
    const int bx = w % GX;
    const int by = (w / GX) % GY;
    const int bz = w / (GX * GY);

    const int x0  = bx * XT;
    const int y0s = by * YT + wv * 4;    // this wave's 4-row strip base
    const int n   = bz / NZCH;
    const int zs  = (bz % NZCH) * ZC;
    const int send = zs + ZC + 3;

    __shared__ float4 c4s[4][SR][CP];
    float4 (*cw)[CP] = c4s[wv];          // wave-private region

    // z rings: [y-out][slot], slot5 freshest
    v2f r01[2][6], r23[2][6];
#pragma unroll
    for (int yo = 0; yo < 2; ++yo)
#pragma unroll
        for (int j = 0; j < 6; ++j) {
            r01[yo][j] = (v2f)(0.f);
            r23[yo][j] = (v2f)(0.f);
        }

    const float C1v = 1e-4f, C2v = 9e-4f;
    float ssum = 0.f;
    const int hw = HH * WW;
    const float* pv = p + (size_t)n * DD * hw;
    const float* tv = t + (size_t)n * DD * hw;

    // ---- B decode: pass1 job = lane (rows 0..7); pass2 lanes<16 (rows 8..9)
    const int xg   = lane & 7;           // x-group, both passes
    const int row1 = lane >> 3;          // 0..7
    const int row2 = 8 + (lane >> 3);    // 8..9 (valid when lane<16)
    const int gy1  = y0s + row1 - 3;
    const int gy2  = y0s + row2 - 3;
    const bool p2  = lane < 16;
    const int cbase = x0 + 4 * xg - 4;   // first loaded column (4-aligned)
    bool qok1[3], qok2[3];
#pragma unroll
    for (int q = 0; q < 3; ++q) {
        bool cok = (unsigned)(cbase + 4 * q) < (unsigned)WW;
        qok1[q] = cok && (unsigned)gy1 < (unsigned)HH;
        qok2[q] = cok && (unsigned)gy2 < (unsigned)HH && p2;
    }

    // ---- C decode: lane = x + 32*yh; outputs y = 2*yh + {0,1} of strip
    const int cx  = lane & 31;
    const int yh  = lane >> 5;           // 0..1
    const int pcr = cx + (cx >> 3);      // swizzled column

    // induction pointers (advance hw per slice)
    const float* pr1 = pv + (size_t)(zs - 3) * hw + gy1 * WW + cbase;
    const float* tr1 = tv + (size_t)(zs - 3) * hw + gy1 * WW + cbase;
    const float* pr2 = pv + (size_t)(zs - 3) * hw + gy2 * WW + cbase;
    const float* tr2 = tv + (size_t)(zs - 3) * hw + gy2 * WW + cbase;

    // x-conv of one job (3 loaded quads -> 4 c4 columns at row r)
    auto xconv = [&](const float4* A, const float4* B, int r) {
        v2f s01[4], s23[4];
#pragma unroll
        for (int e = 0; e < 4; ++e) { s01[e] = (v2f)(0.f); s23[e] = (v2f)(0.f); }
#pragma unroll
        for (int q = 0; q < 3; ++q) {
            const float af[4] = {A[q].x, A[q].y, A[q].z, A[q].w};
            const float bf[4] = {B[q].x, B[q].y, B[q].z, B[q].w};
#pragma unroll
            for (int jj = 0; jj < 4; ++jj) {
                const int i = 4 * q + jj;      // loaded position 0..11
                v2f pt; pt[0] = af[jj]; pt[1] = bf[jj];
                v2f ud; ud[0] = af[jj] + bf[jj]; ud[1] = af[jj] - bf[jj];
                v2f qu = ud * ud;
#pragma unroll
                for (int e = 0; e < 4; ++e) {
                    const int k = i - e - 1;   // tap index
                    if (k >= 0 && k < 7) {
                        s01[e] = gw.g[k] * pt + s01[e];
                        s23[e] = gw.g[k] * qu + s23[e];
                    }
                }
            }
        }
#pragma unroll
        for (int e = 0; e < 4; ++e) {
            int c = 4 * xg + e;
            cw[r][c + (c >> 3)] =
                make_float4(s01[e][0], s01[e][1], s23[e][0], s23[e][1]);
        }
    };

    float4 pfa[3], pfb[3];
    auto prefetch1 = [&](int sx) {
#pragma unroll
        for (int q = 0; q < 3; ++q) {
            pfa[q] = make_float4(0.f, 0.f, 0.f, 0.f);
            pfb[q] = make_float4(0.f, 0.f, 0.f, 0.f);
        }
        if (sx >= 0 && sx < DD && sx < send) {
#pragma unroll
            for (int q = 0; q < 3; ++q) {
                if (qok1[q]) {
                    pfa[q] = *(const float4*)(pr1 + 4 * q);
                    pfb[q] = *(const float4*)(tr1 + 4 * q);
                }
            }
        }
    };

    prefetch1(zs - 3);

    for (int s = zs - 3; s < send; ++s) {
        const bool valid = (s >= 0) && (s < DD);   // wave-uniform

        if (valid) {
            // ---- B pass 1 (all lanes): rows 0..7 of strip halo ----
            xconv(pfa, pfb, row1);
            // ---- B pass 2 (lanes < 16): rows 8..9 ----
            if (p2) {
                float4 a2[3], b2[3];
#pragma unroll
                for (int q = 0; q < 3; ++q) {
                    a2[q] = make_float4(0.f, 0.f, 0.f, 0.f);
                    b2[q] = make_float4(0.f, 0.f, 0.f, 0.f);
                    if (qok2[q]) {
                        a2[q] = *(const float4*)(pr2 + 4 * q);
                        b2[q] = *(const float4*)(tr2 + 4 * q);
                    }
                }
                xconv(a2, b2, row2);
            }
        }

        // ---- prefetch pass-1 rows of slice s+1 ----
        pr1 += hw; tr1 += hw;
        prefetch1(s + 1);
        pr2 += hw; tr2 += hw;

        // ---- C: y-conv from wave-private c4 (DS in-order, no barrier) ----
        v2f m01[2], m23[2];
#pragma unroll
        for (int yo = 0; yo < 2; ++yo) {
            m01[yo] = (v2f)(0.f);
            m23[yo] = (v2f)(0.f);
        }
        if (valid) {
#pragma unroll
            for (int r8 = 0; r8 < 8; ++r8) {
                float4 v = cw[2 * yh + r8][pcr];
                v2f v01; v01[0] = v.x; v01[1] = v.y;
                v2f v23; v23[0] = v.z; v23[1] = v.w;
                if (r8 < 7) {
                    float w2 = gw.g[r8];
                    m01[0] = w2 * v01 + m01[0];
                    m23[0] = w2 * v23 + m23[0];
                }
                if (r8 > 0) {
                    float w2 = gw.g[r8 - 1];
                    m01[1] = w2 * v01 + m01[1];
                    m23[1] = w2 * v23 + m23[1];
                }
            }
        }

        // ---- z rings: consume slot0, shift+FMA, refill ----
#pragma unroll
        for (int yo = 0; yo < 2; ++yo) {
            v2f v01 = m01[yo], v23 = m23[yo];
            v2f cons01 = gw.g[6] * v01 + r01[yo][0];
            v2f cons23 = gw.g[6] * v23 + r23[yo][0];
#pragma unroll
            for (int jj = 0; jj < 5; ++jj) {
                r01[yo][jj] = gw.g[5 - jj] * v01 + r01[yo][jj + 1];
                r23[yo][jj] = gw.g[5 - jj] * v23 + r23[yo][jj + 1];
            }
            r01[yo][5] = gw.g[0] * v01;
            r23[yo][5] = gw.g[0] * v23;

            if (s >= zs + 3) {   // output z = s-3
                float mu1 = cons01[0], mu2 = cons01[1];
                float Eu  = cons23[0], Ew  = cons23[1];
                float mu12 = mu1 * mu2, mu1sq = mu1 * mu1, mu2sq = mu2 * mu2;
                float sumsq = 0.5f  * (Eu + Ew) - mu1sq - mu2sq; // s1+s2
                float s12   = 0.25f * (Eu - Ew) - mu12;          // sigma12
                float num = (2.f * mu12 + C1v) * (2.f * s12 + C2v);
                float den = (mu1sq + mu2sq + C1v) * (sumsq + C2v);
                ssum += num * __builtin_amdgcn_rcpf(den);
            }
        }
    }

    // ---- per-wave reduction, per-wave partial (no cross-wave sync) ----
#pragma unroll
    for (int off = 32; off > 0; off >>= 1)
        ssum += __shfl_down(ssum, off, 64);
    if (lane == 0)
        partial[flat * 4 + wv] = ssum;
}

__global__ __launch_bounds__(256) void ssim_final(
        const float* __restrict__ partial, float* __restrict__ out) {
    float s = 0.f;
    for (int i = threadIdx.x; i < NPART; i += 256) s += partial[i];
#pragma unroll
    for (int off = 32; off > 0; off >>= 1)
        s += __shfl_down(s, off, 64);
    __shared__ float wsum[4];
    int lane = threadIdx.x & 63, wid = threadIdx.x >> 6;
    if (lane == 0) wsum[wid] = s;
    __syncthreads();
    if (threadIdx.x == 0) {
        float tot = wsum[0] + wsum[1] + wsum[2] + wsum[3];
        out[0] = 1.0f - tot / (float)NEL;
    }
}

extern "C" void kernel_launch(void* const* d_in, const int* in_sizes, int n_in,
                              void* d_out, int out_size, void* d_ws, size_t ws_size,
                              hipStream_t stream) {
    const float* p = (const float*)d_in[0];
    const float* t = (const float*)d_in[1];
    float* out = (float*)d_out;
    float* partial = (float*)d_ws;   // NPART floats

    G7 gw;
    {
        double s = 0.0, sig = 7.0 / 6.0;
        double g[7];
        for (int i = 0; i < 7; ++i) {
            double d = (double)i - 3.0;
            g[i] = exp(-d * d / (2.0 * sig * sig));
            s += g[i];
        }
        for (int i = 0; i < 7; ++i) gw.g[i] = (float)(g[i] / s);
    }

    ssim_fused<<<NBLK, NTHR, 0, stream>>>(p, t, partial, gw);
    ssim_final<<<1, 256, 0, stream>>>(partial, out);
}

// Round 12
// 132.985 us; speedup vs baseline: 1.2328x; 1.2328x over previous
//
#include <hip/hip_runtime.h>
#include <math.h>

#define DD 160
#define HH 160
#define WW 160
#define NB 2
#define NEL (NB*DD*HH*WW)   // 8,192,000 voxels

#define XT 32               // x outputs per block
#define YT 16               // y outputs per block
#define ZC 16               // z outputs per block
#define NTHR 256
#define NZCH (DD/ZC)        // 10
#define GX (WW/XT)          // 5
#define GY (HH/YT)          // 10
#define NBLK (GX*GY*NB*NZCH)   // 1000 blocks x 4 waves
#define NPART (NBLK*4)         // per-wave partials

#define HR 22               // halo rows (16 + 6)
#define NJOB (HR*8)         // 176 x-conv jobs (< NTHR; R10 taught: do NOT
                            // spread across all lanes -- masked lanes still
                            // cost full issue)
#define CP 35               // c4 physical pitch in float4 (32 + swizzle)

typedef float v2f __attribute__((ext_vector_type(2)));

struct G7 { float g[7]; };

// Fully fused separable 3D SSIM, v11 = R8 + read-early/compute-late skew.
//  R8 evidence: VALU 29.5us + LDS ~20us + conflicts 4.5us ~= 54 of 59us wall
//  -> pipes serialized. R10 failed because B's VALU burst preceded the
//  ds_reads. This version orders each iteration:
//    barrier; ISSUE C's 8 ds_reads (slice s); B(s+1) VALU burst (other
//    parity, prefetched regs); prefetch(s+2); CONSUME reads (y-conv); ring.
//  The ds_read latency is covered by B's ~200-inst burst via data
//  dependence; sched_barrier(0) after the read issue pins the order.
//  Uniform zero-padding: B always writes its parity (zeros for OOB slices),
//  so the skewed consumer never sees stale data.
//  Frozen: XCD swizzle (FETCH 149->43MB), v2f pk-fma, c4 column swizzle,
//  z register rings, tid<176 B mapping, per-wave partials.
__global__ __launch_bounds__(NTHR, 4) void ssim_fused(
        const float* __restrict__ p, const float* __restrict__ t,
        float* __restrict__ partial, G7 gw) {
    const int tid = threadIdx.x;
    const int lane = tid & 63, wv = tid >> 6;
    const int tx  = tid & 31;            // x output column (phase C)
    const int tyo = tid >> 5;            // 0..7, owns y = 2tyo, 2tyo+1

    // XCD-aware work remap (bijection on [0,NBLK))
    const int flat = blockIdx.x;
    const int w = (flat & 7) * (NBLK / 8) + (flat >> 3);
    const int bx = w % GX;
    const int by = (w / GX) % GY;
    const int bz = w / (GX * GY);

    const int x0 = bx * XT;
    const int y0 = by * YT;
    const int n  = bz / NZCH;
    const int zs = (bz % NZCH) * ZC;
    const int send = zs + ZC + 3;        // one past last staged slice

    __shared__ float4 c4[2][HR][CP];

    // z rings: [y-out][slot], slot5 freshest
    v2f r01[2][6], r23[2][6];
#pragma unroll
    for (int yo = 0; yo < 2; ++yo)
#pragma unroll
        for (int j = 0; j < 6; ++j) {
            r01[yo][j] = (v2f)(0.f);
            r23[yo][j] = (v2f)(0.f);
        }

    const float C1v = 1e-4f, C2v = 9e-4f;
    float ssum = 0.f;
    const int hw = HH * WW;
    const float* pv = p + (size_t)n * DD * hw;
    const float* tv = t + (size_t)n * DD * hw;

    // phase-B job decode (tid < 176): row br, x-group bxg
    const int br = tid >> 3;             // 0..21
    const int bxg = tid & 7;             // 0..7
    const int bgy = y0 + br - 3;
    const bool jok = tid < NJOB;
    const bool browok = jok && (unsigned)bgy < (unsigned)HH;
    const int cbase = x0 + 4 * bxg - 4;  // first loaded column (4-aligned)
    const int pcr = tx + (tx >> 3);      // C-phase swizzled column
    bool qok[3];
#pragma unroll
    for (int q = 0; q < 3; ++q)
        qok[q] = browok && (unsigned)(cbase + 4 * q) < (unsigned)WW;

    // induction pointers for the slice currently being prefetched
    const float* prow = pv + (size_t)(zs - 3) * hw + bgy * WW;
    const float* trow = tv + (size_t)(zs - 3) * hw + bgy * WW;

    float4 pfa[3], pfb[3];
    auto prefetch = [&](int sx) {
#pragma unroll
        for (int q = 0; q < 3; ++q) {
            pfa[q] = make_float4(0.f, 0.f, 0.f, 0.f);
            pfb[q] = make_float4(0.f, 0.f, 0.f, 0.f);
        }
        if (sx >= 0 && sx < DD && sx < send) {
#pragma unroll
            for (int q = 0; q < 3; ++q) {
                if (qok[q]) {
                    pfa[q] = *(const float4*)(prow + cbase + 4 * q);
                    pfb[q] = *(const float4*)(trow + cbase + 4 * q);
                }
            }
        }
    };

    // x-conv of prefetched regs -> c4[par] (zeros propagate for OOB slices)
    auto do_B = [&](int par) {
        if (jok) {
            v2f s01[4], s23[4];
#pragma unroll
            for (int e = 0; e < 4; ++e) { s01[e] = (v2f)(0.f); s23[e] = (v2f)(0.f); }
#pragma unroll
            for (int q = 0; q < 3; ++q) {
                const float af[4] = {pfa[q].x, pfa[q].y, pfa[q].z, pfa[q].w};
                const float bf[4] = {pfb[q].x, pfb[q].y, pfb[q].z, pfb[q].w};
#pragma unroll
                for (int jj = 0; jj < 4; ++jj) {
                    const int i = 4 * q + jj;      // loaded position 0..11
                    v2f pt; pt[0] = af[jj]; pt[1] = bf[jj];
                    v2f ud; ud[0] = af[jj] + bf[jj]; ud[1] = af[jj] - bf[jj];
                    v2f qu = ud * ud;
#pragma unroll
                    for (int e = 0; e < 4; ++e) {
                        const int k = i - e - 1;   // tap index
                        if (k >= 0 && k < 7) {
                            s01[e] = gw.g[k] * pt + s01[e];
                            s23[e] = gw.g[k] * qu + s23[e];
                        }
                    }
                }
            }
#pragma unroll
            for (int e = 0; e < 4; ++e) {
                int c = 4 * bxg + e;
                c4[par][br][c + (c >> 3)] =
                    make_float4(s01[e][0], s01[e][1], s23[e][0], s23[e][1]);
            }
        }
    };

    // ---- prologue: stage slice zs-3 (zeros if OOB), prefetch zs-2 ----
    prefetch(zs - 3);
    do_B((zs - 3) & 1);
    prow += hw; trow += hw;
    prefetch(zs - 2);

    for (int s = zs - 3; s < send; ++s) {
        __syncthreads();   // c4[s&1] (written last iter) visible; also
                           // fences last iter's C reads before this B write.

        // ---- 1) ISSUE C's reads for slice s (latency hidden by B) ----
        const bool cvalid = (s >= 0) && (s < DD);
        float4 cv[8];
        if (cvalid) {
#pragma unroll
            for (int r8 = 0; r8 < 8; ++r8)
                cv[r8] = c4[s & 1][2 * tyo + r8][pcr];
        }
        __builtin_amdgcn_sched_barrier(0);   // pin: reads above, B below

        // ---- 2) B(s+1): VALU burst into the other parity ----
        if (s + 1 < send) do_B((s + 1) & 1);

        // ---- 3) prefetch slice s+2 ----
        prow += hw; trow += hw;
        prefetch(s + 2);

        // ---- 4) consume: y-conv from cv ----
        v2f m01[2], m23[2];
#pragma unroll
        for (int yo = 0; yo < 2; ++yo) {
            m01[yo] = (v2f)(0.f);
            m23[yo] = (v2f)(0.f);
        }
        if (cvalid) {
#pragma unroll
            for (int r8 = 0; r8 < 8; ++r8) {
                float4 v = cv[r8];
                v2f v01; v01[0] = v.x; v01[1] = v.y;
                v2f v23; v23[0] = v.z; v23[1] = v.w;
                if (r8 < 7) {
                    float w2 = gw.g[r8];
                    m01[0] = w2 * v01 + m01[0];
                    m23[0] = w2 * v23 + m23[0];
                }
                if (r8 > 0) {
                    float w2 = gw.g[r8 - 1];
                    m01[1] = w2 * v01 + m01[1];
                    m23[1] = w2 * v23 + m23[1];
                }
            }
        }

        // ---- 5) z rings: consume slot0, shift+FMA, refill ----
#pragma unroll
        for (int yo = 0; yo < 2; ++yo) {
            v2f v01 = m01[yo], v23 = m23[yo];
            v2f cons01 = gw.g[6] * v01 + r01[yo][0];
            v2f cons23 = gw.g[6] * v23 + r23[yo][0];
#pragma unroll
            for (int jj = 0; jj < 5; ++jj) {
                r01[yo][jj] = gw.g[5 - jj] * v01 + r01[yo][jj + 1];
                r23[yo][jj] = gw.g[5 - jj] * v23 + r23[yo][jj + 1];
            }
            r01[yo][5] = gw.g[0] * v01;
            r23[yo][5] = gw.g[0] * v23;

            if (s >= zs + 3) {   // output z = s-3
                float mu1 = cons01[0], mu2 = cons01[1];
                float Eu  = cons23[0], Ew  = cons23[1];
                float mu12 = mu1 * mu2, mu1sq = mu1 * mu1, mu2sq = mu2 * mu2;
                float sumsq = 0.5f  * (Eu + Ew) - mu1sq - mu2sq; // s1+s2
                float s12   = 0.25f * (Eu - Ew) - mu12;          // sigma12
                float num = (2.f * mu12 + C1v) * (2.f * s12 + C2v);
                float den = (mu1sq + mu2sq + C1v) * (sumsq + C2v);
                ssum += num * __builtin_amdgcn_rcpf(den);
            }
        }
    }

    // ---- per-wave reduction, per-wave partial (no final barrier) ----
#pragma unroll
    for (int off = 32; off > 0; off >>= 1)
        ssum += __shfl_down(ssum, off, 64);
    if (lane == 0)
        partial[flat * 4 + wv] = ssum;
}

__global__ __launch_bounds__(256) void ssim_final(
        const float* __restrict__ partial, float* __restrict__ out) {
    float s = 0.f;
    for (int i = threadIdx.x; i < NPART; i += 256) s += partial[i];
#pragma unroll
    for (int off = 32; off > 0; off >>= 1)
        s += __shfl_down(s, off, 64);
    __shared__ float wsum[4];
    int lane = threadIdx.x & 63, wid = threadIdx.x >> 6;
    if (lane == 0) wsum[wid] = s;
    __syncthreads();
    if (threadIdx.x == 0) {
        float tot = wsum[0] + wsum[1] + wsum[2] + wsum[3];
        out[0] = 1.0f - tot / (float)NEL;
    }
}

extern "C" void kernel_launch(void* const* d_in, const int* in_sizes, int n_in,
                              void* d_out, int out_size, void* d_ws, size_t ws_size,
                              hipStream_t stream) {
    const float* p = (const float*)d_in[0];
    const float* t = (const float*)d_in[1];
    float* out = (float*)d_out;
    float* partial = (float*)d_ws;   // NPART floats

    G7 gw;
    {
        double s = 0.0, sig = 7.0 / 6.0;
        double g[7];
        for (int i = 0; i < 7; ++i) {
            double d = (double)i - 3.0;
            g[i] = exp(-d * d / (2.0 * sig * sig));
            s += g[i];
        }
        for (int i = 0; i < 7; ++i) gw.g[i] = (float)(g[i] / s);
    }

    ssim_fused<<<NBLK, NTHR, 0, stream>>>(p, t, partial, gw);
    ssim_final<<<1, 256, 0, stream>>>(partial, out);
}

// Round 13
// 131.391 us; speedup vs baseline: 1.2477x; 1.0121x over previous
//
#include <hip/hip_runtime.h>
#include <math.h>

#define DD 160
#define HH 160
#define WW 160
#define NB 2
#define NEL (NB*DD*HH*WW)   // 8,192,000 voxels

#define XT 32               // x outputs per block (4 waves x 8 columns)
#define YT 16               // y outputs per block
#define ZC 16               // z outputs per block
#define NTHR 256
#define NZCH (DD/ZC)        // 10
#define GX (WW/XT)          // 5
#define GY (HH/YT)          // 10
#define NBLK (GX*GY*NB*NZCH)   // 1000 blocks x 4 waves
#define NPART (NBLK*4)         // per-wave partials

#define WX 8                // x columns per wave
#define HR 22               // staged halo rows (16 + 6)
#define CPW 9               // c4 pitch in float4 (8 cols + 1 pad)

typedef float v2f __attribute__((ext_vector_type(2)));

struct G7 { float g[7]; };

// Fully fused separable 3D SSIM, v13 = BARRIER-FREE wave-column strips.
//  R8..R12 evidence: VALU 29.5us + LDS ~20us busy vs 59us wall with zero
//  overlap; three scheduling tweaks (R10 skew, R11 y-strips, R12 read-early)
//  all failed -> the stall is the per-slice s_barrier convoy itself.
//  R11's mistake was wave-splitting along y (halo rows duplicated 2.5x).
//  This version splits along X: each wave owns 8 x-columns x 16 y.
//   * wave's c4 tile (22 rows x 8 cols) is written AND read only by itself;
//     y-conv is column-local -> no cross-wave LDS sharing at all.
//   * within-wave ds_write -> ds_read is ordered by the in-order per-wave
//     DS pipe -> NO __syncthreads in the K-loop, single buffer, no parity.
//   * B work/wave = 44 jobs = exactly R8's 176/4: zero work duplication
//     (only the global x-halo widens: 14 loaded cols per wave; HBM at 9%).
//   * waves self-pace; ~15 independent waves/CU cover each other's stalls.
//  Frozen: XCD swizzle, v2f pk-fma, z register rings, register prefetch,
//  in-register SSIM, per-wave partials.
__global__ __launch_bounds__(NTHR, 4) void ssim_fused(
        const float* __restrict__ p, const float* __restrict__ t,
        float* __restrict__ partial, G7 gw) {
    const int tid  = threadIdx.x;
    const int lane = tid & 63;
    const int wv   = tid >> 6;

    // XCD-aware work remap (bijection on [0,NBLK))
    const int flat = blockIdx.x;
    const int w = (flat & 7) * (NBLK / 8) + (flat >> 3);
    const int bx = w % GX;
    const int by = (w / GX) % GY;
    const int bz = w / (GX * GY);

    const int x0w = bx * XT + wv * WX;   // this wave's x base
    const int y0  = by * YT;
    const int n   = bz / NZCH;
    const int zs  = (bz % NZCH) * ZC;
    const int send = zs + ZC + 3;        // one past last staged slice

    __shared__ float4 c4s[4][HR][CPW];
    float4 (*cw)[CPW] = c4s[wv];         // wave-private c4 tile

    // z rings: [y-out][slot], slot5 freshest
    v2f r01[2][6], r23[2][6];
#pragma unroll
    for (int yo = 0; yo < 2; ++yo)
#pragma unroll
        for (int j = 0; j < 6; ++j) {
            r01[yo][j] = (v2f)(0.f);
            r23[yo][j] = (v2f)(0.f);
        }

    const float C1v = 1e-4f, C2v = 9e-4f;
    float ssum = 0.f;
    const int hw = HH * WW;
    const float* pv = p + (size_t)n * DD * hw;
    const float* tv = t + (size_t)n * DD * hw;

    // ---- B decode (lane < 44): row 0..21, x-group 0..1 ----
    const bool jok = lane < 2 * HR;
    const int brow = lane >> 1;          // 0..21
    const int grp  = lane & 1;           // 0..1 (4 output cols each)
    const int bgy  = y0 + brow - 3;
    const bool browok = jok && (unsigned)bgy < (unsigned)HH;
    const int cbase = x0w + 4 * grp - 4; // first loaded column (4-aligned)
    bool qok[3];
#pragma unroll
    for (int q = 0; q < 3; ++q)
        qok[q] = browok && (unsigned)(cbase + 4 * q) < (unsigned)WW;

    // ---- C decode: lane = x(0..7) + 8*yg(0..7); outputs y = 2yg,2yg+1 ----
    const int cx = lane & 7;
    const int yg = lane >> 3;

    // induction pointers for the slice currently prefetched
    const float* prow = pv + (size_t)(zs - 3) * hw + bgy * WW;
    const float* trow = tv + (size_t)(zs - 3) * hw + bgy * WW;

    float4 pfa[3], pfb[3];
    auto prefetch = [&](int sx) {
#pragma unroll
        for (int q = 0; q < 3; ++q) {
            pfa[q] = make_float4(0.f, 0.f, 0.f, 0.f);
            pfb[q] = make_float4(0.f, 0.f, 0.f, 0.f);
        }
        if (sx >= 0 && sx < DD && sx < send) {
#pragma unroll
            for (int q = 0; q < 3; ++q) {
                if (qok[q]) {
                    pfa[q] = *(const float4*)(prow + cbase + 4 * q);
                    pfb[q] = *(const float4*)(trow + cbase + 4 * q);
                }
            }
        }
    };

    prefetch(zs - 3);

    for (int s = zs - 3; s < send; ++s) {
        const bool valid = (s >= 0) && (s < DD);   // wave-uniform

        v2f m01[2], m23[2];
#pragma unroll
        for (int yo = 0; yo < 2; ++yo) {
            m01[yo] = (v2f)(0.f);
            m23[yo] = (v2f)(0.f);
        }

        if (valid) {
            // ---- B(s): x-conv of prefetched regs -> own c4 tile ----
            if (jok) {
                v2f s01[4], s23[4];
#pragma unroll
                for (int e = 0; e < 4; ++e) { s01[e] = (v2f)(0.f); s23[e] = (v2f)(0.f); }
#pragma unroll
                for (int q = 0; q < 3; ++q) {
                    const float af[4] = {pfa[q].x, pfa[q].y, pfa[q].z, pfa[q].w};
                    const float bf[4] = {pfb[q].x, pfb[q].y, pfb[q].z, pfb[q].w};
#pragma unroll
                    for (int jj = 0; jj < 4; ++jj) {
                        const int i = 4 * q + jj;      // loaded position 0..11
                        v2f pt; pt[0] = af[jj]; pt[1] = bf[jj];
                        v2f ud; ud[0] = af[jj] + bf[jj]; ud[1] = af[jj] - bf[jj];
                        v2f qu = ud * ud;
#pragma unroll
                        for (int e = 0; e < 4; ++e) {
                            const int k = i - e - 1;   // tap index
                            if (k >= 0 && k < 7) {
                                s01[e] = gw.g[k] * pt + s01[e];
                                s23[e] = gw.g[k] * qu + s23[e];
                            }
                        }
                    }
                }
#pragma unroll
                for (int e = 0; e < 4; ++e)
                    cw[brow][4 * grp + e] =
                        make_float4(s01[e][0], s01[e][1], s23[e][0], s23[e][1]);
            }

            // ---- prefetch slice s+1 (latency covered by C + ring) ----
            prow += hw; trow += hw;
            prefetch(s + 1);

            // ---- C(s): y-conv from own tile (in-order DS, no barrier) ----
#pragma unroll
            for (int r8 = 0; r8 < 8; ++r8) {
                float4 v = cw[2 * yg + r8][cx];
                v2f v01; v01[0] = v.x; v01[1] = v.y;
                v2f v23; v23[0] = v.z; v23[1] = v.w;
                if (r8 < 7) {
                    float w2 = gw.g[r8];
                    m01[0] = w2 * v01 + m01[0];
                    m23[0] = w2 * v23 + m23[0];
                }
                if (r8 > 0) {
                    float w2 = gw.g[r8 - 1];
                    m01[1] = w2 * v01 + m01[1];
                    m23[1] = w2 * v23 + m23[1];
                }
            }
        } else {
            // OOB slice contributes zeros; keep prefetch pipeline moving
            prow += hw; trow += hw;
            prefetch(s + 1);
        }

        // ---- z rings: consume slot0, shift+FMA, refill ----
#pragma unroll
        for (int yo = 0; yo < 2; ++yo) {
            v2f v01 = m01[yo], v23 = m23[yo];
            v2f cons01 = gw.g[6] * v01 + r01[yo][0];
            v2f cons23 = gw.g[6] * v23 + r23[yo][0];
#pragma unroll
            for (int jj = 0; jj < 5; ++jj) {
                r01[yo][jj] = gw.g[5 - jj] * v01 + r01[yo][jj + 1];
                r23[yo][jj] = gw.g[5 - jj] * v23 + r23[yo][jj + 1];
            }
            r01[yo][5] = gw.g[0] * v01;
            r23[yo][5] = gw.g[0] * v23;

            if (s >= zs + 3) {   // output z = s-3
                float mu1 = cons01[0], mu2 = cons01[1];
                float Eu  = cons23[0], Ew  = cons23[1];
                float mu12 = mu1 * mu2, mu1sq = mu1 * mu1, mu2sq = mu2 * mu2;
                float sumsq = 0.5f  * (Eu + Ew) - mu1sq - mu2sq; // s1+s2
                float s12   = 0.25f * (Eu - Ew) - mu12;          // sigma12
                float num = (2.f * mu12 + C1v) * (2.f * s12 + C2v);
                float den = (mu1sq + mu2sq + C1v) * (sumsq + C2v);
                ssum += num * __builtin_amdgcn_rcpf(den);
            }
        }
    }

    // ---- per-wave reduction, per-wave partial (no block sync at all) ----
#pragma unroll
    for (int off = 32; off > 0; off >>= 1)
        ssum += __shfl_down(ssum, off, 64);
    if (lane == 0)
        partial[flat * 4 + wv] = ssum;
}

__global__ __launch_bounds__(256) void ssim_final(
        const float* __restrict__ partial, float* __restrict__ out) {
    float s = 0.f;
    for (int i = threadIdx.x; i < NPART; i += 256) s += partial[i];
#pragma unroll
    for (int off = 32; off > 0; off >>= 1)
        s += __shfl_down(s, off, 64);
    __shared__ float wsum[4];
    int lane = threadIdx.x & 63, wid = threadIdx.x >> 6;
    if (lane == 0) wsum[wid] = s;
    __syncthreads();
    if (threadIdx.x == 0) {
        float tot = wsum[0] + wsum[1] + wsum[2] + wsum[3];
        out[0] = 1.0f - tot / (float)NEL;
    }
}

extern "C" void kernel_launch(void* const* d_in, const int* in_sizes, int n_in,
                              void* d_out, int out_size, void* d_ws, size_t ws_size,
                              hipStream_t stream) {
    const float* p = (const float*)d_in[0];
    const float* t = (const float*)d_in[1];
    float* out = (float*)d_out;
    float* partial = (float*)d_ws;   // NPART floats

    G7 gw;
    {
        double s = 0.0, sig = 7.0 / 6.0;
        double g[7];
        for (int i = 0; i < 7; ++i) {
            double d = (double)i - 3.0;
            g[i] = exp(-d * d / (2.0 * sig * sig));
            s += g[i];
        }
        for (int i = 0; i < 7; ++i) gw.g[i] = (float)(g[i] / s);
    }

    ssim_fused<<<NBLK, NTHR, 0, stream>>>(p, t, partial, gw);
    ssim_final<<<1, 256, 0, stream>>>(partial, out);
}